// Round 17
// baseline (521.781 us; speedup 1.0000x reference)
//
#include <hip/hip_runtime.h>
#include <hip/hip_fp16.h>

#define FEAT 128
#define BKT_SHIFT 8
#define CHUNK 4096

struct half4 { __half2 lo, hi; };

// ---------------- radix pass A: histogram by src>>8 over raw edge list ----------------
__global__ __launch_bounds__(256) void k_bhist_src(const int* __restrict__ srcp, int E, int BL,
                                                   int* __restrict__ gh) {
    __shared__ int h[256];
    int tid = threadIdx.x, b = blockIdx.x;
    h[tid] = 0;
    __syncthreads();
    int cb = b * CHUNK;
    for (int i = tid; i < CHUNK; i += 256) {
        int e = cb + i;
        if (e < E) atomicAdd(&h[srcp[e] >> BKT_SHIFT], 1);
    }
    __syncthreads();
    gh[tid * BL + b] = h[tid];   // bucket-major
}

// ---------------- radix pass B: histogram by dst>>8 over src-sorted int2 edges ----------------
__global__ __launch_bounds__(256) void k_bhist_dst(const int2* __restrict__ eb, int E, int BL,
                                                   int* __restrict__ gh) {
    __shared__ int h[256];
    int tid = threadIdx.x, b = blockIdx.x;
    h[tid] = 0;
    __syncthreads();
    int cb = b * CHUNK;
    for (int i = tid; i < CHUNK; i += 256) {
        int e = cb + i;
        if (e < E) atomicAdd(&h[eb[e].y >> BKT_SHIFT], 1);
    }
    __syncthreads();
    gh[tid * BL + b] = h[tid];
}

// ---------------- generic 3-phase exclusive scan (512 elems / block) ----------------
__global__ __launch_bounds__(256) void k_s1(const int* __restrict__ g, int len,
                                            int* __restrict__ bsum) {
    int tid = threadIdx.x;
    int i0 = blockIdx.x * 512 + tid * 2;
    int v0 = (i0 < len) ? g[i0] : 0;
    int v1 = (i0 + 1 < len) ? g[i0 + 1] : 0;
    __shared__ int s[256];
    s[tid] = v0 + v1;
    __syncthreads();
    for (int off = 128; off > 0; off >>= 1) {
        if (tid < off) s[tid] += s[tid + off];
        __syncthreads();
    }
    if (tid == 0) bsum[blockIdx.x] = s[0];
}

__global__ __launch_bounds__(256) void k_s2(int* __restrict__ bsum, int nb) {
    int tid = threadIdx.x;
    __shared__ int s[256];
    int v = (tid < nb) ? bsum[tid] : 0;
    s[tid] = v;
    __syncthreads();
    for (int off = 1; off < 256; off <<= 1) {
        int t = (tid >= off) ? s[tid - off] : 0;
        __syncthreads();
        s[tid] += t;
        __syncthreads();
    }
    if (tid < nb) bsum[tid] = s[tid] - v;   // exclusive
}

__global__ __launch_bounds__(256) void k_s3(const int* __restrict__ g, int len,
                                            const int* __restrict__ bsum,
                                            int* __restrict__ out) {
    int tid = threadIdx.x;
    int i0 = blockIdx.x * 512 + tid * 2;
    int v0 = (i0 < len) ? g[i0] : 0;
    int v1 = (i0 + 1 < len) ? g[i0 + 1] : 0;
    __shared__ int s[256];
    int pair = v0 + v1;
    s[tid] = pair;
    __syncthreads();
    for (int off = 1; off < 256; off <<= 1) {
        int t = (tid >= off) ? s[tid - off] : 0;
        __syncthreads();
        s[tid] += t;
        __syncthreads();
    }
    int excl = s[tid] - pair + bsum[blockIdx.x];
    if (i0 < len)     out[i0] = excl;
    if (i0 + 1 < len) out[i0 + 1] = excl + v0;
}

// ---------------- radix scatter A: raw edges -> ebuf2 sorted by src-bucket ----------------
__global__ __launch_bounds__(256) void k_bscat_src(const int* __restrict__ ei, int E, int BL,
                                                   const int* __restrict__ gscan,
                                                   int2* __restrict__ eb) {
    __shared__ int lcur[256];
    int tid = threadIdx.x, b = blockIdx.x;
    lcur[tid] = gscan[tid * BL + b];
    __syncthreads();
    int cb = b * CHUNK;
    for (int i = tid; i < CHUNK; i += 256) {
        int e = cb + i;
        if (e < E) {
            int s = ei[e], d = ei[E + e];
            int pos = atomicAdd(&lcur[s >> BKT_SHIFT], 1);
            eb[pos] = make_int2(s, d);
        }
    }
}

// ---------------- radix scatter B: ebuf2 -> ebuf sorted by dst-bucket (quasi-stable) ----------------
__global__ __launch_bounds__(256) void k_bscat_dst(const int2* __restrict__ ebin, int E, int BL,
                                                   const int* __restrict__ gscan,
                                                   int2* __restrict__ ebout) {
    __shared__ int lcur[256];
    int tid = threadIdx.x, b = blockIdx.x;
    lcur[tid] = gscan[tid * BL + b];
    __syncthreads();
    int cb = b * CHUNK;
    for (int i = tid; i < CHUNK; i += 256) {
        int e = cb + i;
        if (e < E) {
            int2 ed = ebin[e];
            int pos = atomicAdd(&lcur[ed.y >> BKT_SHIFT], 1);
            ebout[pos] = ed;
        }
    }
}

// ---------------- per-bucket deg count -> row_ptr + dis ----------------
__global__ __launch_bounds__(256) void k_bdeg(const int2* __restrict__ ebuf,
                                              const int* __restrict__ gscan, int BL,
                                              int n, int E,
                                              int* __restrict__ row_ptr,
                                              float* __restrict__ dis) {
    __shared__ int sdeg[256], soff[256];
    int tid = threadIdx.x, k = blockIdx.x;
    int base = k << BKT_SHIFT;
    int start = gscan[k * BL];
    int end = gscan[(k + 1) * BL];
    sdeg[tid] = 0;
    __syncthreads();
    for (int e = start + tid; e < end; e += 256)
        atomicAdd(&sdeg[ebuf[e].y - base], 1);
    __syncthreads();
    int v = sdeg[tid];
    soff[tid] = v;
    __syncthreads();
    for (int off = 1; off < 256; off <<= 1) {
        int t = (tid >= off) ? soff[tid - off] : 0;
        __syncthreads();
        soff[tid] += t;
        __syncthreads();
    }
    int node = base + tid;
    if (node < n) {
        row_ptr[node] = start + soff[tid] - v;
        dis[node] = rsqrtf((float)(1 + v));
    }
    if (k == 0 && tid == 0) row_ptr[n] = E;
}

// ---------------- per-bucket CSR fill (preserves ~src order within segments) ----------------
__global__ __launch_bounds__(256) void k_bfill(const int2* __restrict__ ebuf,
                                               const int* __restrict__ gscan, int BL,
                                               int n, int E,
                                               const int* __restrict__ row_ptr,
                                               const float* __restrict__ dis,
                                               int2* __restrict__ csr) {
    __shared__ int scur[256];
    int tid = threadIdx.x, k = blockIdx.x;
    int base = k << BKT_SHIFT;
    int start = gscan[k * BL];
    int end = gscan[(k + 1) * BL];
    int node = base + tid;
    scur[tid] = (node < n) ? row_ptr[node] : 0;
    __syncthreads();
    for (int e = start + tid; e < end; e += 256) {
        int2 ed = ebuf[e];
        int pos = atomicAdd(&scur[ed.y - base], 1);
        csr[pos] = make_int2(ed.x, __float_as_int(dis[ed.x] * dis[ed.y]));
    }
}

// ---------------- GEMM: out16[n,128] = A @ W; A = f32 (A32) or fp16 (A16) ----------------
__global__ __launch_bounds__(256) void k_gemm128(const float* __restrict__ A32,
                                                 const __half* __restrict__ A16,
                                                 const float* __restrict__ W,
                                                 __half* __restrict__ out16, int n) {
    __shared__ float As[32][64];
    __shared__ float Ws[32][128];
    int tid = threadIdx.x;
    int row0b = blockIdx.x * 64;
    int tx = tid & 31, ty = tid >> 5;
    int col0 = tx * 4, r0 = ty * 8;
    float4 acc[8];
#pragma unroll
    for (int i = 0; i < 8; ++i) acc[i] = make_float4(0.f, 0.f, 0.f, 0.f);

    int sr = tid & 63;
    int sq = (tid >> 6) * 4;
    int grow = row0b + sr;

    for (int kc = 0; kc < 128; kc += 32) {
#pragma unroll
        for (int j = 0; j < 2; ++j) {
            int qk = sq + j * 16;
            float4 v = make_float4(0.f, 0.f, 0.f, 0.f);
            if (grow < n) {
                if (A32) {
                    v = *(const float4*)(A32 + (size_t)grow * FEAT + kc + qk);
                } else {
                    half4 h = *(const half4*)(A16 + (size_t)grow * FEAT + kc + qk);
                    float2 l = __half22float2(h.lo), u = __half22float2(h.hi);
                    v = make_float4(l.x, l.y, u.x, u.y);
                }
            }
            As[qk + 0][sr] = v.x; As[qk + 1][sr] = v.y;
            As[qk + 2][sr] = v.z; As[qk + 3][sr] = v.w;
        }
#pragma unroll
        for (int j = 0; j < 4; ++j) {
            int idx = tid + j * 256;
            int wk = idx >> 5;
            int wc = (idx & 31) * 4;
            *(float4*)&Ws[wk][wc] = *(const float4*)(W + (size_t)(kc + wk) * 128 + wc);
        }
        __syncthreads();
#pragma unroll
        for (int k = 0; k < 32; ++k) {
            float4 w = *(float4*)&Ws[k][col0];
            float a[8];
            *(float4*)&a[0] = *(float4*)&As[k][r0];
            *(float4*)&a[4] = *(float4*)&As[k][r0 + 4];
#pragma unroll
            for (int i = 0; i < 8; ++i) {
                acc[i].x += a[i] * w.x;
                acc[i].y += a[i] * w.y;
                acc[i].z += a[i] * w.z;
                acc[i].w += a[i] * w.w;
            }
        }
        __syncthreads();
    }
#pragma unroll
    for (int i = 0; i < 8; ++i) {
        int row = row0b + r0 + i;
        if (row < n) {
            half4 h;
            h.lo = __floats2half2_rn(acc[i].x, acc[i].y);
            h.hi = __floats2half2_rn(acc[i].z, acc[i].w);
            *(half4*)(out16 + (size_t)row * FEAT + col0) = h;
        }
    }
}

// ---------------- head GEMM: [mu|ls] = A(f32) @ [Wmu|Wls] + [bmu|bls] ----------------
__global__ __launch_bounds__(256) void k_gemm_head(const float* __restrict__ A,
                                                   const float* __restrict__ Wmu,
                                                   const float* __restrict__ Wls,
                                                   const float* __restrict__ bmu,
                                                   const float* __restrict__ bls,
                                                   float* __restrict__ mu,
                                                   float* __restrict__ ls, int n) {
    __shared__ float As[32][64];
    __shared__ float Ws[32][128];
    int tid = threadIdx.x;
    int row0b = blockIdx.x * 64;
    int tx = tid & 31, ty = tid >> 5;
    int col0 = tx * 4, r0 = ty * 8;
    float4 acc[8];
#pragma unroll
    for (int i = 0; i < 8; ++i) acc[i] = make_float4(0.f, 0.f, 0.f, 0.f);

    int sr = tid & 63;
    int sq = (tid >> 6) * 4;
    int grow = row0b + sr;

    for (int kc = 0; kc < 128; kc += 32) {
#pragma unroll
        for (int j = 0; j < 2; ++j) {
            int qk = sq + j * 16;
            float4 v = make_float4(0.f, 0.f, 0.f, 0.f);
            if (grow < n) v = *(const float4*)(A + (size_t)grow * FEAT + kc + qk);
            As[qk + 0][sr] = v.x; As[qk + 1][sr] = v.y;
            As[qk + 2][sr] = v.z; As[qk + 3][sr] = v.w;
        }
#pragma unroll
        for (int j = 0; j < 4; ++j) {
            int idx = tid + j * 256;
            int wk = idx >> 5;
            int wc = (idx & 31) * 4;
            const float* Wp = (wc < 64) ? (Wmu + (size_t)(kc + wk) * 64 + wc)
                                        : (Wls + (size_t)(kc + wk) * 64 + (wc - 64));
            *(float4*)&Ws[wk][wc] = *(const float4*)Wp;
        }
        __syncthreads();
#pragma unroll
        for (int k = 0; k < 32; ++k) {
            float4 w = *(float4*)&Ws[k][col0];
            float a[8];
            *(float4*)&a[0] = *(float4*)&As[k][r0];
            *(float4*)&a[4] = *(float4*)&As[k][r0 + 4];
#pragma unroll
            for (int i = 0; i < 8; ++i) {
                acc[i].x += a[i] * w.x;
                acc[i].y += a[i] * w.y;
                acc[i].z += a[i] * w.z;
                acc[i].w += a[i] * w.w;
            }
        }
        __syncthreads();
    }
    bool is_mu = (col0 < 64);
    int c = is_mu ? col0 : col0 - 64;
    const float* bp = is_mu ? (bmu + c) : (bls + c);
    float4 b = *(const float4*)bp;
    float* op = is_mu ? mu : ls;
#pragma unroll
    for (int i = 0; i < 8; ++i) {
        int row = row0b + r0 + i;
        if (row < n)
            *(float4*)(op + (size_t)row * 64 + c) =
                make_float4(acc[i].x + b.x, acc[i].y + b.y, acc[i].z + b.z, acc[i].w + b.w);
    }
}

// ---------------- aggregation: all-fp16 in; fp16 and/or f32 out ----------------
__global__ __launch_bounds__(256) void k_agg(const __half* __restrict__ t16,
                                             const int* __restrict__ row_ptr,
                                             const int2* __restrict__ csr,
                                             const float* __restrict__ dis,
                                             const float* __restrict__ bias,
                                             __half* __restrict__ out16,
                                             float* __restrict__ out32,
                                             int n, int do_relu) {
    int wave = (int)((blockIdx.x * blockDim.x + threadIdx.x) >> 6);
    int lane = threadIdx.x & 63;
    if (wave >= n) return;
    int node = wave;
    float d = dis[node];
    float sw = d * d;
    float2 self = __half22float2(*((const __half2*)(t16 + ((size_t)node << 7)) + lane));
    float2 acc[8];
    acc[0].x = self.x * sw; acc[0].y = self.y * sw;
#pragma unroll
    for (int i = 1; i < 8; ++i) { acc[i].x = 0.f; acc[i].y = 0.f; }
    int e = row_ptr[node], e1 = row_ptr[node + 1];
    for (; e + 8 <= e1; e += 8) {
        int2 c[8];
#pragma unroll
        for (int i = 0; i < 8; ++i) c[i] = csr[e + i];
        __half2 hv[8];
#pragma unroll
        for (int i = 0; i < 8; ++i)
            hv[i] = *((const __half2*)(t16 + ((size_t)c[i].x << 7)) + lane);
#pragma unroll
        for (int i = 0; i < 8; ++i) {
            float w = __int_as_float(c[i].y);
            float2 v = __half22float2(hv[i]);
            acc[i].x += w * v.x;
            acc[i].y += w * v.y;
        }
    }
    for (; e + 4 <= e1; e += 4) {
        int2 c[4];
#pragma unroll
        for (int i = 0; i < 4; ++i) c[i] = csr[e + i];
#pragma unroll
        for (int i = 0; i < 4; ++i) {
            float w = __int_as_float(c[i].y);
            float2 v = __half22float2(*((const __half2*)(t16 + ((size_t)c[i].x << 7)) + lane));
            acc[i].x += w * v.x;
            acc[i].y += w * v.y;
        }
    }
    for (; e < e1; ++e) {
        int2 c0 = csr[e];
        float w0 = __int_as_float(c0.y);
        float2 v0 = __half22float2(*((const __half2*)(t16 + ((size_t)c0.x << 7)) + lane));
        acc[0].x += w0 * v0.x; acc[0].y += w0 * v0.y;
    }
#pragma unroll
    for (int i = 1; i < 8; ++i) { acc[0].x += acc[i].x; acc[0].y += acc[i].y; }
    if (bias) {
        acc[0].x += bias[lane << 1];
        acc[0].y += bias[(lane << 1) + 1];
    }
    if (do_relu) {
        acc[0].x = fmaxf(acc[0].x, 0.f);
        acc[0].y = fmaxf(acc[0].y, 0.f);
    }
    if (out16)
        *((__half2*)(out16 + ((size_t)node << 7)) + lane) = __floats2half2_rn(acc[0].x, acc[0].y);
    if (out32)
        *(float2*)(out32 + ((size_t)node << 7) + (lane << 1)) = acc[0];
}

extern "C" void kernel_launch(void* const* d_in, const int* in_sizes, int n_in,
                              void* d_out, int out_size, void* d_ws, size_t ws_size,
                              hipStream_t stream) {
    const float* x   = (const float*)d_in[0];
    const int*   ei  = (const int*)d_in[1];
    const float* W1  = (const float*)d_in[2];
    const float* b1  = (const float*)d_in[3];
    const float* W2  = (const float*)d_in[4];
    const float* b2  = (const float*)d_in[5];
    const float* W3  = (const float*)d_in[6];
    const float* b3  = (const float*)d_in[7];
    const float* Wmu = (const float*)d_in[8];
    const float* bmu = (const float*)d_in[9];
    const float* Wls = (const float*)d_in[10];
    const float* bls = (const float*)d_in[11];

    int n = in_sizes[0] / FEAT;    // 50000
    int E = in_sizes[1] / 2;       // 1,600,000

    char* ws = (char*)d_ws;
    size_t off = 0;
    auto alloc = [&](size_t bytes) {
        void* p = ws + off;
        off = (off + bytes + 255) & ~(size_t)255;
        return p;
    };
    float*  Bt32    = (float*)alloc((size_t)n * FEAT * 4);   // head input (f32)
    __half* Bt16    = (__half*)alloc((size_t)n * FEAT * 2);
    __half* Bh16    = (__half*)alloc((size_t)n * FEAT * 2);
    float*  dis     = (float*)alloc((size_t)n * 4);
    int*    row_ptr = (int*)alloc((size_t)(n + 1) * 4);
    int*    bsum    = (int*)alloc(256 * 4);
    int2*   csr     = (int2*)alloc((size_t)E * 8);
    int2*   ebuf    = (int2*)alloc((size_t)E * 8);
    int2*   ebuf2   = (int2*)alloc((size_t)E * 8);

    int BL  = (E + CHUNK - 1) / CHUNK;     // 391 edge blocks
    int lenh = 256 * BL;
    int* gh1    = (int*)alloc((size_t)lenh * 4);
    int* gscan1 = (int*)alloc((size_t)lenh * 4);
    int* gh2    = (int*)alloc((size_t)lenh * 4);
    int* gscan2 = (int*)alloc((size_t)lenh * 4);

    int NBK = (n + 255) >> BKT_SHIFT;      // 196 buckets
    int nbs = (lenh + 511) / 512;

    // radix pass A: sort edges by src-bucket (locality for agg gathers)
    k_bhist_src<<<BL, 256, 0, stream>>>(ei, E, BL, gh1);
    k_s1<<<nbs, 256, 0, stream>>>(gh1, lenh, bsum);
    k_s2<<<1, 256, 0, stream>>>(bsum, nbs);
    k_s3<<<nbs, 256, 0, stream>>>(gh1, lenh, bsum, gscan1);
    k_bscat_src<<<BL, 256, 0, stream>>>(ei, E, BL, gscan1, ebuf2);
    // radix pass B: stable sort by dst-bucket
    k_bhist_dst<<<BL, 256, 0, stream>>>(ebuf2, E, BL, gh2);
    k_s1<<<nbs, 256, 0, stream>>>(gh2, lenh, bsum);
    k_s2<<<1, 256, 0, stream>>>(bsum, nbs);
    k_s3<<<nbs, 256, 0, stream>>>(gh2, lenh, bsum, gscan2);
    k_bscat_dst<<<BL, 256, 0, stream>>>(ebuf2, E, BL, gscan2, ebuf);
    // CSR build
    k_bdeg<<<NBK, 256, 0, stream>>>(ebuf, gscan2, BL, n, E, row_ptr, dis);
    k_bfill<<<NBK, 256, 0, stream>>>(ebuf, gscan2, BL, n, E, row_ptr, dis, csr);

    int gb = (n + 63) / 64;
    int ab = (n + 3) / 4;
    float* mu = (float*)d_out;
    float* ls = (float*)d_out + (size_t)n * 64;

    k_gemm128<<<gb, 256, 0, stream>>>(x, nullptr, W1, Bt16, n);
    k_agg<<<ab, 256, 0, stream>>>(Bt16, row_ptr, csr, dis, b1, Bh16, nullptr, n, 1);
    k_gemm128<<<gb, 256, 0, stream>>>(nullptr, Bh16, W2, Bt16, n);
    k_agg<<<ab, 256, 0, stream>>>(Bt16, row_ptr, csr, dis, b2, Bh16, nullptr, n, 1);
    k_gemm128<<<gb, 256, 0, stream>>>(nullptr, Bh16, W3, Bt16, n);
    k_agg<<<ab, 256, 0, stream>>>(Bt16, row_ptr, csr, dis, b3, Bh16, nullptr, n, 1);
    // g = A_norm @ h3 (shared by both heads); write f32 for the head GEMM
    k_agg<<<ab, 256, 0, stream>>>(Bh16, row_ptr, csr, dis, nullptr, nullptr, Bt32, n, 0);
    k_gemm_head<<<gb, 256, 0, stream>>>(Bt32, Wmu, Wls, bmu, bls, mu, ls, n);
}